// Round 11
// baseline (290.577 us; speedup 1.0000x reference)
//
#include <hip/hip_runtime.h>
#include <hip/hip_fp16.h>

#define NN 256
#define VV 25
#define TT 128
#define CIN 64
#define CO 64
#define RR 9
#define HH4 18
#define HH5 6

typedef unsigned int uint;
typedef unsigned short ushort;
typedef __attribute__((ext_vector_type(8))) short bf16x8;
typedef __attribute__((ext_vector_type(4))) float f32x4;

__device__ __forceinline__ float silu_f(float v) {
  return __fdividef(v, 1.0f + __expf(-v));
}
__device__ __forceinline__ __half2 u2h(uint u) {
  union { uint x; __half2 h; } c; c.x = u; return c.h;
}
__device__ __forceinline__ uint h2u(__half2 h) {
  union { __half2 h; uint x; } c; c.h = h; return c.x;
}
__device__ __forceinline__ ushort f2bf(float f) {
  union { float f; uint u; } c; c.f = f;
  const uint u = c.u + 0x7FFFu + ((c.u >> 16) & 1u);
  return (ushort)(u >> 16);
}

// ---------------------------------------------------------------------------
// k1 [x3 DUPLICATED this round for counter visibility: grid 19200, fold %6400;
// idempotent writes]: per (n,v): coalesced x tile -> fp16 LDS transpose;
// x3 = x@W3+b3 -> bf16 [c][t] tile -> coalesced x3g[n][v][th4][c9][tp16];
// xm = col sums (f32 register path).
// ---------------------------------------------------------------------------
__global__ __launch_bounds__(128) void k1_proj(
    const float* __restrict__ x, const float* __restrict__ W3,
    const float* __restrict__ b3, uint* __restrict__ x3g,
    float* __restrict__ xm) {
  const int blk = blockIdx.x % (NN * VV);   // duplicate-fold
  const int tid = threadIdx.x;
  __shared__ __align__(16) __half xt[TT * 66];     // 16,896 B
  __shared__ __align__(16) float xmp[2][64];
  __shared__ __align__(16) ushort ptile[RR * TT];  // [c][t] bf16

  const float4* src = (const float4*)(x + (size_t)blk * TT * CIN);
  float4 r[16];
  #pragma unroll
  for (int k = 0; k < 16; ++k) r[k] = src[k * 128 + tid];
  #pragma unroll
  for (int k = 0; k < 16; ++k) {
    const int idx = k * 128 + tid;
    const int t = idx >> 4, c = (idx & 15) * 4;
    *(__half2*)(&xt[t * 66 + c])     = __floats2half2_rn(r[k].x, r[k].y);
    *(__half2*)(&xt[t * 66 + c + 2]) = __floats2half2_rn(r[k].z, r[k].w);
  }
  float4 cs = r[0];
  #pragma unroll
  for (int k = 1; k < 16; ++k) {
    cs.x += r[k].x; cs.y += r[k].y; cs.z += r[k].z; cs.w += r[k].w;
  }
  #pragma unroll
  for (int m = 16; m < 64; m <<= 1) {
    cs.x += __shfl_xor(cs.x, m); cs.y += __shfl_xor(cs.y, m);
    cs.z += __shfl_xor(cs.z, m); cs.w += __shfl_xor(cs.w, m);
  }
  if ((tid & 63) < 16) *(float4*)(&xmp[tid >> 6][(tid & 15) * 4]) = cs;
  __syncthreads();
  if (tid < 64) xm[(size_t)blk * 64 + tid] = xmp[0][tid] + xmp[1][tid];

  float acc[RR];
  #pragma unroll
  for (int j = 0; j < RR; ++j) acc[j] = b3[j];
  const __half* xrow = xt + tid * 66;
  #pragma unroll 8
  for (int c2 = 0; c2 < 32; ++c2) {
    const __half2 hv = *(const __half2*)(&xrow[c2 * 2]);
    const float x0 = __low2float(hv), x1 = __high2float(hv);
    #pragma unroll
    for (int j = 0; j < RR; ++j) {
      acc[j] = fmaf(x0, W3[(c2 * 2 + 0) * RR + j], acc[j]);
      acc[j] = fmaf(x1, W3[(c2 * 2 + 1) * RR + j], acc[j]);
    }
  }
  #pragma unroll
  for (int j = 0; j < RR; ++j) ptile[j * TT + tid] = f2bf(acc[j]);
  __syncthreads();

  const uint* tu = (const uint*)ptile;
  uint* dst = x3g + (size_t)blk * 576;
  #pragma unroll
  for (int it = 0; it < 5; ++it) {
    const int i = it * 128 + tid;
    if (i < 576) {
      const int c = i >> 6, tp = i & 63;
      dst[(tp >> 4) * 144 + c * 16 + (tp & 15)] = tu[i];
    }
  }
}

// ---------------------------------------------------------------------------
// k2: per n: means from xm, rel MLP (9->18->9), + A -> LDS f32 [c][u][v],
// then branchless packed bf16 coalesced stores -> h2g[n][c9][u32][v32].
// ---------------------------------------------------------------------------
__global__ __launch_bounds__(128) void k2_h(
    const float* __restrict__ xm, const float* __restrict__ A,
    const float* __restrict__ W1, const float* __restrict__ b1,
    const float* __restrict__ W2, const float* __restrict__ b2,
    const float* __restrict__ W4a, const float* __restrict__ b4a,
    const float* __restrict__ W4b, const float* __restrict__ b4b,
    uint* __restrict__ h2g) {
  const int n = blockIdx.x;
  const int tid = threadIdx.x;
  __shared__ float m1[VV][RR + 1];
  __shared__ float m2[VV][RR + 1];
  __shared__ float hf[RR][32][32];
  const float* xmn = xm + (size_t)n * VV * CIN;
  for (int i = tid; i < 2 * VV * RR; i += 128) {
    const int which = (i >= VV * RR);
    const int idx = which ? i - VV * RR : i;
    const int v = idx / RR, c = idx - v * RR;
    const float* W = which ? W2 : W1;
    const float* b = which ? b2 : b1;
    const float* row = xmn + v * CIN;
    float s = 0.f;
    #pragma unroll
    for (int k = 0; k < CIN; ++k) s = fmaf(row[k], W[k * RR + c], s);
    s = s * (1.0f / TT) + b[c];
    if (which) m2[v][c] = s; else m1[v][c] = s;
  }
  for (int i = tid; i < RR * VV * 7; i += 128) {
    const int c = i / 175, r = i - c * 175;
    const int u = r / 7, v = 25 + (r - u * 7);
    hf[c][u][v] = 0.f;
  }
  __syncthreads();
  for (int p = tid; p < VV * VV; p += 128) {
    const int u = p / VV, v2 = p - u * VV;
    float rel[RR];
    #pragma unroll
    for (int j = 0; j < RR; ++j) rel[j] = m1[u][j] - m2[v2][j];
    float t1[HH4];
    #pragma unroll
    for (int k = 0; k < HH4; ++k) {
      float s = b4a[k];
      #pragma unroll
      for (int j = 0; j < RR; ++j) s = fmaf(rel[j], W4a[j * HH4 + k], s);
      t1[k] = silu_f(s);
    }
    const float av = A[u * VV + v2];
    #pragma unroll
    for (int j = 0; j < RR; ++j) {
      float s = b4b[j];
      #pragma unroll
      for (int k = 0; k < HH4; ++k) s = fmaf(t1[k], W4b[k * RR + j], s);
      hf[j][u][v2] = silu_f(s) + av;
    }
  }
  __syncthreads();
  uint* hb = h2g + (size_t)n * (RR * 512);
  for (int i = tid; i < RR * 512; i += 128) {
    const int c = i >> 9, r = i & 511;
    const int u = r >> 4, vp = r & 15;
    const float lo = hf[c][u][vp * 2], hi = hf[c][u][vp * 2 + 1];
    const uint w = (u < VV) ? ((uint)f2bf(lo) | ((uint)f2bf(hi) << 16)) : 0u;
    hb[i] = w;
  }
}

// ---------------------------------------------------------------------------
// k3 [x3 DUPLICATED this round: grid 3072, fold %1024; idempotent writes]:
// per (n, th4): stage x3 slice -> LDS [c][t32][v40]; A-frags prefetched;
// 9 MFMA f32; per-lane 9->6 silu -> a5s; coalesced 6->64 epilogue.
// ---------------------------------------------------------------------------
__global__ __launch_bounds__(256, 4) void k3_out(
    const uint* __restrict__ x3g, const ushort* __restrict__ h2g,
    const float* __restrict__ W5a, const float* __restrict__ b5a,
    const float* __restrict__ W5b, const float* __restrict__ b5b,
    float* __restrict__ out) {
  const int bid = blockIdx.x % 1024;    // duplicate-fold
  const int n = bid >> 2, th = bid & 3;
  const int tid = threadIdx.x;
  __shared__ __align__(16) ushort xlds[RR * 32 * 40];  // 23,040 B
  __shared__ __align__(16) uint a5s[VV * 32 * 3];      //  9,600 B

  const int wid = tid >> 6, lane = tid & 63;
  const int nt = wid & 1, mt = wid >> 1;
  const int lr = lane & 15, kb = lane >> 4;
  const int tl = nt * 16 + lr;
  const ushort* hbase =
      h2g + (size_t)n * (RR * 1024) + (mt * 16 + lr) * 32 + kb * 8;
  bf16x8 Af[RR];
  #pragma unroll
  for (int c = 0; c < RR; ++c) Af[c] = *(const bf16x8*)(hbase + c * 1024);

  const uint* srcu = x3g + (size_t)n * (VV * 576) + th * 144;
  for (int i = tid; i < VV * 144; i += 256) {
    const int v = i / 144, r = i - v * 144;
    const uint w = srcu[v * 576 + r];
    const int c = r >> 4, tpl = r & 15;
    const int base = c * 1280 + (tpl * 2) * 40 + v;
    xlds[base]      = (ushort)(w & 0xffffu);
    xlds[base + 40] = (ushort)(w >> 16);
  }
  for (int i = tid; i < RR * 32 * 7; i += 256) {
    const int c = i / 224, r2 = i - c * 224;
    const int t = r2 / 7, v = 25 + (r2 - t * 7);
    xlds[c * 1280 + t * 40 + v] = 0;
  }
  const int cq = (tid & 15) * 4;
  float4 wb[HH5];
  #pragma unroll
  for (int k = 0; k < HH5; ++k) wb[k] = *(const float4*)(W5b + k * CO + cq);
  const float4 bb = *(const float4*)(b5b + cq);
  __syncthreads();

  f32x4 acc[RR];
  #pragma unroll
  for (int c = 0; c < RR; ++c) {
    const bf16x8 Bf = *(const bf16x8*)(xlds + c * 1280 + tl * 40 + kb * 8);
    f32x4 z = {0.f, 0.f, 0.f, 0.f};
    acc[c] = __builtin_amdgcn_mfma_f32_16x16x32_bf16(Af[c], Bf, z, 0, 0, 0);
  }

  #pragma unroll
  for (int j = 0; j < 4; ++j) {
    const int u = mt * 16 + kb * 4 + j;
    if (u < VV) {
      float a5v[HH5];
      #pragma unroll
      for (int k = 0; k < HH5; ++k) {
        float s = b5a[k];
        #pragma unroll
        for (int c = 0; c < RR; ++c) s = fmaf(acc[c][j], W5a[c * HH5 + k], s);
        a5v[k] = silu_f(s);
      }
      uint* d = a5s + (u * 32 + tl) * 3;
      d[0] = h2u(__floats2half2_rn(a5v[0], a5v[1]));
      d[1] = h2u(__floats2half2_rn(a5v[2], a5v[3]));
      d[2] = h2u(__floats2half2_rn(a5v[4], a5v[5]));
    }
  }
  __syncthreads();

  #pragma unroll 2
  for (int it = 0; it < 50; ++it) {
    const int q = it * 16 + (tid >> 4);
    const int u = q >> 5, tl2 = q & 31;
    const uint w0 = a5s[q * 3 + 0];
    const uint w1 = a5s[q * 3 + 1];
    const uint w2 = a5s[q * 3 + 2];
    const __half2 p01 = u2h(w0), p23 = u2h(w1), p45 = u2h(w2);
    const float a0 = __low2float(p01), a1 = __high2float(p01);
    const float a2 = __low2float(p23), a3 = __high2float(p23);
    const float a4 = __low2float(p45), a5 = __high2float(p45);
    float4 y;
    y.x = silu_f(bb.x + a0 * wb[0].x + a1 * wb[1].x + a2 * wb[2].x +
                 a3 * wb[3].x + a4 * wb[4].x + a5 * wb[5].x);
    y.y = silu_f(bb.y + a0 * wb[0].y + a1 * wb[1].y + a2 * wb[2].y +
                 a3 * wb[3].y + a4 * wb[4].y + a5 * wb[5].y);
    y.z = silu_f(bb.z + a0 * wb[0].z + a1 * wb[1].z + a2 * wb[2].z +
                 a3 * wb[3].z + a4 * wb[4].z + a5 * wb[5].z);
    y.w = silu_f(bb.w + a0 * wb[0].w + a1 * wb[1].w + a2 * wb[2].w +
                 a3 * wb[3].w + a4 * wb[4].w + a5 * wb[5].w);
    float* orow = out +
        (((size_t)(n * VV + u)) * TT + th * 32 + tl2) * CO + cq;
    *(float4*)orow = y;
  }
}

extern "C" void kernel_launch(void* const* d_in, const int* in_sizes, int n_in,
                              void* d_out, int out_size, void* d_ws, size_t ws_size,
                              hipStream_t stream) {
  const float* x   = (const float*)d_in[0];
  const float* A   = (const float*)d_in[1];
  const float* W1  = (const float*)d_in[2];
  const float* b1  = (const float*)d_in[3];
  const float* W2  = (const float*)d_in[4];
  const float* b2  = (const float*)d_in[5];
  const float* W3  = (const float*)d_in[6];
  const float* b3  = (const float*)d_in[7];
  const float* W4a = (const float*)d_in[8];
  const float* b4a = (const float*)d_in[9];
  const float* W4b = (const float*)d_in[10];
  const float* b4b = (const float*)d_in[11];
  const float* W5a = (const float*)d_in[12];
  const float* b5a = (const float*)d_in[13];
  const float* W5b = (const float*)d_in[14];
  const float* b5b = (const float*)d_in[15];
  float* out = (float*)d_out;

  char* ws = (char*)d_ws;
  uint*   x3g = (uint*)ws;                // 6400*576*4 = 14,745,600 B
  float*  xm  = (float*)(ws + 14745600);  //  1,638,400 B
  uint*   h2g = (uint*)(ws + 16384000);   //  4,718,592 B

  hipLaunchKernelGGL(k1_proj, dim3(NN * VV * 3), dim3(128), 0, stream,
                     x, W3, b3, x3g, xm);
  hipLaunchKernelGGL(k2_h, dim3(NN), dim3(128), 0, stream,
                     xm, A, W1, b1, W2, b2, W4a, b4a, W4b, b4b, h2g);
  hipLaunchKernelGGL(k3_out, dim3(1024 * 3), dim3(256), 0, stream,
                     x3g, (const ushort*)h2g, W5a, b5a, W5b, b5b, out);
}

// Round 12
// 161.320 us; speedup vs baseline: 1.8012x; 1.8012x over previous
//
#include <hip/hip_runtime.h>
#include <hip/hip_fp16.h>

#define NN 256
#define VV 25
#define TT 128
#define CIN 64
#define CO 64
#define RR 9
#define HH4 18
#define HH5 6

typedef unsigned int uint;
typedef unsigned short ushort;
typedef __attribute__((ext_vector_type(8))) _Float16 f16x8;
typedef __attribute__((ext_vector_type(4))) float f32x4;

__device__ __forceinline__ float silu_f(float v) {
  return __fdividef(v, 1.0f + __expf(-v));
}
__device__ __forceinline__ __half2 u2h(uint u) {
  union { uint x; __half2 h; } c; c.x = u; return c.h;
}
__device__ __forceinline__ uint h2u(__half2 h) {
  union { __half2 h; uint x; } c; c.h = h; return c.x;
}

// ---------------------------------------------------------------------------
// k1: per (n,v): coalesced x tile -> fp16 LDS transpose; x3^T = W3^T @ x^T
// via 8x2 mfma_f32_16x16x32_f16 (bias in C operand) -> ptile[c][t] f16 ->
// coalesced x3g[n][v][th4][c9][tp16]; xm = col sums (f32 register path).
// ---------------------------------------------------------------------------
__global__ __launch_bounds__(128) void k1_proj(
    const float* __restrict__ x, const float* __restrict__ W3,
    const float* __restrict__ b3, uint* __restrict__ x3g,
    float* __restrict__ xm) {
  const int blk = blockIdx.x;            // n*V + v
  const int tid = threadIdx.x;
  __shared__ __align__(16) __half xt[TT * 66];     // 16,896 B
  __shared__ __align__(16) float xmp[2][64];
  __shared__ __align__(16) __half ptile[RR * TT];  // [c][t] f16

  const float4* src = (const float4*)(x + (size_t)blk * TT * CIN);
  float4 r[16];
  #pragma unroll
  for (int k = 0; k < 16; ++k) r[k] = src[k * 128 + tid];
  #pragma unroll
  for (int k = 0; k < 16; ++k) {
    const int idx = k * 128 + tid;
    const int t = idx >> 4, c = (idx & 15) * 4;
    *(__half2*)(&xt[t * 66 + c])     = __floats2half2_rn(r[k].x, r[k].y);
    *(__half2*)(&xt[t * 66 + c + 2]) = __floats2half2_rn(r[k].z, r[k].w);
  }
  // column partial sums from f32 registers (mean path stays fp32)
  float4 cs = r[0];
  #pragma unroll
  for (int k = 1; k < 16; ++k) {
    cs.x += r[k].x; cs.y += r[k].y; cs.z += r[k].z; cs.w += r[k].w;
  }
  #pragma unroll
  for (int m = 16; m < 64; m <<= 1) {
    cs.x += __shfl_xor(cs.x, m); cs.y += __shfl_xor(cs.y, m);
    cs.z += __shfl_xor(cs.z, m); cs.w += __shfl_xor(cs.w, m);
  }
  if ((tid & 63) < 16) *(float4*)(&xmp[tid >> 6][(tid & 15) * 4]) = cs;

  // A-frags: W3^T rows m=c (pad 16), k = kf*32 + kb*8 + e
  const int wave = tid >> 6, lane = tid & 63;
  const int lr = lane & 15, kb = lane >> 4;
  const int li = (lr < RR) ? lr : 0;
  f16x8 af0, af1;
  #pragma unroll
  for (int e = 0; e < 8; ++e) {
    const float w0 = W3[(kb * 8 + e) * RR + li];
    const float w1 = W3[(32 + kb * 8 + e) * RR + li];
    af0[e] = (_Float16)((lr < RR) ? w0 : 0.f);
    af1[e] = (_Float16)((lr < RR) ? w1 : 0.f);
  }
  f32x4 cini;
  #pragma unroll
  for (int j = 0; j < 4; ++j) {
    const int row = kb * 4 + j;
    cini[j] = (row < RR) ? b3[(row < RR) ? row : 0] : 0.f;
  }
  __syncthreads();
  if (tid < 64) xm[(size_t)blk * 64 + tid] = xmp[0][tid] + xmp[1][tid];

  // 4 t-tiles per wave, 2 K-steps each
  #pragma unroll
  for (int i = 0; i < 4; ++i) {
    const int tt = wave * 4 + i;
    const ushort* bp = (const ushort*)xt + (tt * 16 + lr) * 66 + kb * 8;
    const f16x8 b0 = *(const f16x8*)bp;
    const f16x8 b1 = *(const f16x8*)(bp + 32);
    f32x4 d = __builtin_amdgcn_mfma_f32_16x16x32_f16(af0, b0, cini, 0, 0, 0);
    d = __builtin_amdgcn_mfma_f32_16x16x32_f16(af1, b1, d, 0, 0, 0);
    #pragma unroll
    for (int j = 0; j < 4; ++j) {
      const int row = kb * 4 + j;
      if (row < RR) ptile[row * TT + tt * 16 + lr] = __float2half(d[j]);
    }
  }
  __syncthreads();

  // coalesced out: uint i of [c][t] -> global [th][c][tp16]
  const uint* tu = (const uint*)ptile;
  uint* dst = x3g + (size_t)blk * 576;
  #pragma unroll
  for (int it = 0; it < 5; ++it) {
    const int i = it * 128 + tid;
    if (i < 576) {
      const int c = i >> 6, tp = i & 63;
      dst[(tp >> 4) * 144 + c * 16 + (tp & 15)] = tu[i];
    }
  }
}

// ---------------------------------------------------------------------------
// k2: per n: means from xm, rel MLP (9->18->9), + A -> LDS f32 [c][u][v],
// then branchless packed f16 coalesced stores -> h2g[n][c9][u32][v32].
// ---------------------------------------------------------------------------
__global__ __launch_bounds__(128) void k2_h(
    const float* __restrict__ xm, const float* __restrict__ A,
    const float* __restrict__ W1, const float* __restrict__ b1,
    const float* __restrict__ W2, const float* __restrict__ b2,
    const float* __restrict__ W4a, const float* __restrict__ b4a,
    const float* __restrict__ W4b, const float* __restrict__ b4b,
    uint* __restrict__ h2g) {
  const int n = blockIdx.x;
  const int tid = threadIdx.x;
  __shared__ float m1[VV][RR + 1];
  __shared__ float m2[VV][RR + 1];
  __shared__ float hf[RR][32][32];
  const float* xmn = xm + (size_t)n * VV * CIN;
  for (int i = tid; i < 2 * VV * RR; i += 128) {
    const int which = (i >= VV * RR);
    const int idx = which ? i - VV * RR : i;
    const int v = idx / RR, c = idx - v * RR;
    const float* W = which ? W2 : W1;
    const float* b = which ? b2 : b1;
    const float* row = xmn + v * CIN;
    float s = 0.f;
    #pragma unroll
    for (int k = 0; k < CIN; ++k) s = fmaf(row[k], W[k * RR + c], s);
    s = s * (1.0f / TT) + b[c];
    if (which) m2[v][c] = s; else m1[v][c] = s;
  }
  for (int i = tid; i < RR * VV * 7; i += 128) {
    const int c = i / 175, r = i - c * 175;
    const int u = r / 7, v = 25 + (r - u * 7);
    hf[c][u][v] = 0.f;
  }
  __syncthreads();
  for (int p = tid; p < VV * VV; p += 128) {
    const int u = p / VV, v2 = p - u * VV;
    float rel[RR];
    #pragma unroll
    for (int j = 0; j < RR; ++j) rel[j] = m1[u][j] - m2[v2][j];
    float t1[HH4];
    #pragma unroll
    for (int k = 0; k < HH4; ++k) {
      float s = b4a[k];
      #pragma unroll
      for (int j = 0; j < RR; ++j) s = fmaf(rel[j], W4a[j * HH4 + k], s);
      t1[k] = silu_f(s);
    }
    const float av = A[u * VV + v2];
    #pragma unroll
    for (int j = 0; j < RR; ++j) {
      float s = b4b[j];
      #pragma unroll
      for (int k = 0; k < HH4; ++k) s = fmaf(t1[k], W4b[k * RR + j], s);
      hf[j][u][v2] = silu_f(s) + av;
    }
  }
  __syncthreads();
  uint* hb = h2g + (size_t)n * (RR * 512);
  for (int i = tid; i < RR * 512; i += 128) {
    const int c = i >> 9, r = i & 511;
    const int u = r >> 4, vp = r & 15;
    const float lo = hf[c][u][vp * 2], hi = hf[c][u][vp * 2 + 1];
    const uint w = (u < VV) ? h2u(__floats2half2_rn(lo, hi)) : 0u;
    hb[i] = w;
  }
}

// ---------------------------------------------------------------------------
// k3: per (n, th4): stage x3 slice -> LDS [c][t32][v40] f16; A-frags (h)
// prefetched from global; 9 MFMA f32; per-lane 9->6 silu -> a5s; coalesced
// 6->64 silu epilogue (float4 stores). LDS 32.6 KB -> 4 blocks/CU.
// ---------------------------------------------------------------------------
__global__ __launch_bounds__(256, 4) void k3_out(
    const uint* __restrict__ x3g, const ushort* __restrict__ h2g,
    const float* __restrict__ W5a, const float* __restrict__ b5a,
    const float* __restrict__ W5b, const float* __restrict__ b5b,
    float* __restrict__ out) {
  const int bid = blockIdx.x;           // n*4 + th
  const int n = bid >> 2, th = bid & 3;
  const int tid = threadIdx.x;
  __shared__ __align__(16) ushort xlds[RR * 32 * 40];  // 23,040 B
  __shared__ __align__(16) uint a5s[VV * 32 * 3];      //  9,600 B

  const int wid = tid >> 6, lane = tid & 63;
  const int nt = wid & 1, mt = wid >> 1;
  const int lr = lane & 15, kb = lane >> 4;
  const int tl = nt * 16 + lr;
  const ushort* hbase =
      h2g + (size_t)n * (RR * 1024) + (mt * 16 + lr) * 32 + kb * 8;
  f16x8 Af[RR];
  #pragma unroll
  for (int c = 0; c < RR; ++c) Af[c] = *(const f16x8*)(hbase + c * 1024);

  const uint* srcu = x3g + (size_t)n * (VV * 576) + th * 144;
  for (int i = tid; i < VV * 144; i += 256) {
    const int v = i / 144, r = i - v * 144;
    const uint w = srcu[v * 576 + r];
    const int c = r >> 4, tpl = r & 15;
    const int base = c * 1280 + (tpl * 2) * 40 + v;
    xlds[base]      = (ushort)(w & 0xffffu);
    xlds[base + 40] = (ushort)(w >> 16);
  }
  for (int i = tid; i < RR * 32 * 7; i += 256) {
    const int c = i / 224, r2 = i - c * 224;
    const int t = r2 / 7, v = 25 + (r2 - t * 7);
    xlds[c * 1280 + t * 40 + v] = 0;
  }
  const int cq = (tid & 15) * 4;
  float4 wb[HH5];
  #pragma unroll
  for (int k = 0; k < HH5; ++k) wb[k] = *(const float4*)(W5b + k * CO + cq);
  const float4 bb = *(const float4*)(b5b + cq);
  __syncthreads();

  f32x4 acc[RR];
  #pragma unroll
  for (int c = 0; c < RR; ++c) {
    const f16x8 Bf = *(const f16x8*)(xlds + c * 1280 + tl * 40 + kb * 8);
    f32x4 z = {0.f, 0.f, 0.f, 0.f};
    acc[c] = __builtin_amdgcn_mfma_f32_16x16x32_f16(Af[c], Bf, z, 0, 0, 0);
  }

  #pragma unroll
  for (int j = 0; j < 4; ++j) {
    const int u = mt * 16 + kb * 4 + j;
    if (u < VV) {
      float a5v[HH5];
      #pragma unroll
      for (int k = 0; k < HH5; ++k) {
        float s = b5a[k];
        #pragma unroll
        for (int c = 0; c < RR; ++c) s = fmaf(acc[c][j], W5a[c * HH5 + k], s);
        a5v[k] = silu_f(s);
      }
      uint* d = a5s + (u * 32 + tl) * 3;
      d[0] = h2u(__floats2half2_rn(a5v[0], a5v[1]));
      d[1] = h2u(__floats2half2_rn(a5v[2], a5v[3]));
      d[2] = h2u(__floats2half2_rn(a5v[4], a5v[5]));
    }
  }
  __syncthreads();

  #pragma unroll 2
  for (int it = 0; it < 50; ++it) {
    const int q = it * 16 + (tid >> 4);
    const int u = q >> 5, tl2 = q & 31;
    const uint w0 = a5s[q * 3 + 0];
    const uint w1 = a5s[q * 3 + 1];
    const uint w2 = a5s[q * 3 + 2];
    const __half2 p01 = u2h(w0), p23 = u2h(w1), p45 = u2h(w2);
    const float a0 = __low2float(p01), a1 = __high2float(p01);
    const float a2 = __low2float(p23), a3 = __high2float(p23);
    const float a4 = __low2float(p45), a5 = __high2float(p45);
    float4 y;
    y.x = silu_f(bb.x + a0 * wb[0].x + a1 * wb[1].x + a2 * wb[2].x +
                 a3 * wb[3].x + a4 * wb[4].x + a5 * wb[5].x);
    y.y = silu_f(bb.y + a0 * wb[0].y + a1 * wb[1].y + a2 * wb[2].y +
                 a3 * wb[3].y + a4 * wb[4].y + a5 * wb[5].y);
    y.z = silu_f(bb.z + a0 * wb[0].z + a1 * wb[1].z + a2 * wb[2].z +
                 a3 * wb[3].z + a4 * wb[4].z + a5 * wb[5].z);
    y.w = silu_f(bb.w + a0 * wb[0].w + a1 * wb[1].w + a2 * wb[2].w +
                 a3 * wb[3].w + a4 * wb[4].w + a5 * wb[5].w);
    float* orow = out +
        (((size_t)(n * VV + u)) * TT + th * 32 + tl2) * CO + cq;
    *(float4*)orow = y;
  }
}

extern "C" void kernel_launch(void* const* d_in, const int* in_sizes, int n_in,
                              void* d_out, int out_size, void* d_ws, size_t ws_size,
                              hipStream_t stream) {
  const float* x   = (const float*)d_in[0];
  const float* A   = (const float*)d_in[1];
  const float* W1  = (const float*)d_in[2];
  const float* b1  = (const float*)d_in[3];
  const float* W2  = (const float*)d_in[4];
  const float* b2  = (const float*)d_in[5];
  const float* W3  = (const float*)d_in[6];
  const float* b3  = (const float*)d_in[7];
  const float* W4a = (const float*)d_in[8];
  const float* b4a = (const float*)d_in[9];
  const float* W4b = (const float*)d_in[10];
  const float* b4b = (const float*)d_in[11];
  const float* W5a = (const float*)d_in[12];
  const float* b5a = (const float*)d_in[13];
  const float* W5b = (const float*)d_in[14];
  const float* b5b = (const float*)d_in[15];
  float* out = (float*)d_out;

  char* ws = (char*)d_ws;
  uint* x3g = (uint*)ws;                 // 6400*576*4 = 14,745,600 B
  float* xm = (float*)(ws + 14745600);   //  1,638,400 B
  uint*  h2g = (uint*)(ws + 16384000);   //  4,718,592 B

  hipLaunchKernelGGL(k1_proj, dim3(NN * VV), dim3(128), 0, stream,
                     x, W3, b3, x3g, xm);
  hipLaunchKernelGGL(k2_h, dim3(NN), dim3(128), 0, stream,
                     xm, A, W1, b1, W2, b2, W4a, b4a, W4b, b4b, h2g);
  hipLaunchKernelGGL(k3_out, dim3(NN * 4), dim3(256), 0, stream,
                     x3g, (const ushort*)h2g, W5a, b5a, W5b, b5b, out);
}

// Round 13
// 148.415 us; speedup vs baseline: 1.9579x; 1.0870x over previous
//
#include <hip/hip_runtime.h>
#include <hip/hip_fp16.h>

#define NN 256
#define VV 25
#define TT 128
#define CIN 64
#define CO 64
#define RR 9
#define HH4 18
#define HH5 6
#define TQ 16
#define NT 8

typedef unsigned int uint;

__device__ __forceinline__ float silu_f(float v) {
  return __fdividef(v, 1.0f + __expf(-v));
}
__device__ __forceinline__ __half2 u2h(uint u) {
  union { uint x; __half2 h; } c; c.x = u; return c.h;
}
__device__ __forceinline__ uint h2u(__half2 h) {
  union { __half2 h; uint x; } c; c.h = h; return c.x;
}

// ---------------------------------------------------------------------------
// k1 (exact R7): per (n,v): coalesced load of 32KB x tile -> HALF LDS
// transpose; x3 = x@W3+b3 packed as 5 half2-planes [n*NT+tq][c][v][t16];
// xm = column sums of x from f32 registers.
// ---------------------------------------------------------------------------
__global__ __launch_bounds__(128) void k1_proj(
    const float* __restrict__ x, const float* __restrict__ W3,
    const float* __restrict__ b3, uint* __restrict__ x3g,
    float* __restrict__ xm) {
  const int blk = blockIdx.x;            // n*V + v
  const int n = blk / VV, v = blk - n * VV;
  const int tid = threadIdx.x;
  __shared__ __align__(16) __half xt[TT * 66];   // 16,896 B
  __shared__ __align__(16) float xmp[2][64];

  const float4* src = (const float4*)(x + (size_t)blk * TT * CIN);
  float4 r[16];
  #pragma unroll
  for (int k = 0; k < 16; ++k) r[k] = src[k * 128 + tid];
  #pragma unroll
  for (int k = 0; k < 16; ++k) {
    const int idx = k * 128 + tid;
    const int t = idx >> 4, c = (idx & 15) * 4;
    *(__half2*)(&xt[t * 66 + c])     = __floats2half2_rn(r[k].x, r[k].y);
    *(__half2*)(&xt[t * 66 + c + 2]) = __floats2half2_rn(r[k].z, r[k].w);
  }
  // column partial sums from f32 registers (mean path stays fp32)
  float4 cs = r[0];
  #pragma unroll
  for (int k = 1; k < 16; ++k) {
    cs.x += r[k].x; cs.y += r[k].y; cs.z += r[k].z; cs.w += r[k].w;
  }
  #pragma unroll
  for (int m = 16; m < 64; m <<= 1) {
    cs.x += __shfl_xor(cs.x, m); cs.y += __shfl_xor(cs.y, m);
    cs.z += __shfl_xor(cs.z, m); cs.w += __shfl_xor(cs.w, m);
  }
  if ((tid & 63) < 16) *(float4*)(&xmp[tid >> 6][(tid & 15) * 4]) = cs;
  __syncthreads();
  if (tid < 64) xm[(size_t)blk * 64 + tid] = xmp[0][tid] + xmp[1][tid];

  // x3 row for t = tid: b32 LDS reads (stride 66 halves -> conflict-free)
  float acc[RR];
  #pragma unroll
  for (int j = 0; j < RR; ++j) acc[j] = b3[j];
  const __half* xrow = xt + tid * 66;
  #pragma unroll 8
  for (int c2 = 0; c2 < 32; ++c2) {
    const __half2 hv = *(const __half2*)(&xrow[c2 * 2]);
    const float x0 = __low2float(hv), x1 = __high2float(hv);
    #pragma unroll
    for (int j = 0; j < RR; ++j) {
      acc[j] = fmaf(x0, W3[(c2 * 2 + 0) * RR + j], acc[j]);
      acc[j] = fmaf(x1, W3[(c2 * 2 + 1) * RR + j], acc[j]);
    }
  }
  uint w[5];
  w[0] = h2u(__floats2half2_rn(acc[0], acc[1]));
  w[1] = h2u(__floats2half2_rn(acc[2], acc[3]));
  w[2] = h2u(__floats2half2_rn(acc[4], acc[5]));
  w[3] = h2u(__floats2half2_rn(acc[6], acc[7]));
  w[4] = h2u(__floats2half2_rn(acc[8], 0.f));
  const int tq = tid >> 4, t = tid & 15;
  uint* dst = x3g + (size_t)(n * NT + tq) * (5 * VV * TQ) + v * TQ + t;
  #pragma unroll
  for (int c = 0; c < 5; ++c) dst[c * (VV * TQ)] = w[c];
}

// ---------------------------------------------------------------------------
// k2 (exact R7): per n: means from xm, rel MLP (9->18->9), + A ->
// h [n][u*V+v][5 uints]
// ---------------------------------------------------------------------------
__global__ __launch_bounds__(128) void k2_h(
    const float* __restrict__ xm, const float* __restrict__ A,
    const float* __restrict__ W1, const float* __restrict__ b1,
    const float* __restrict__ W2, const float* __restrict__ b2,
    const float* __restrict__ W4a, const float* __restrict__ b4a,
    const float* __restrict__ W4b, const float* __restrict__ b4b,
    uint* __restrict__ h2g) {
  const int n = blockIdx.x;
  const int tid = threadIdx.x;
  __shared__ float m1[VV][RR + 1];
  __shared__ float m2[VV][RR + 1];
  const float* xmn = xm + (size_t)n * VV * CIN;
  for (int i = tid; i < 2 * VV * RR; i += 128) {
    const int which = (i >= VV * RR);
    const int idx = which ? i - VV * RR : i;
    const int v = idx / RR, c = idx - v * RR;
    const float* W = which ? W2 : W1;
    const float* b = which ? b2 : b1;
    const float* row = xmn + v * CIN;
    float s = 0.f;
    #pragma unroll
    for (int k = 0; k < CIN; ++k) s = fmaf(row[k], W[k * RR + c], s);
    s = s * (1.0f / TT) + b[c];
    if (which) m2[v][c] = s; else m1[v][c] = s;
  }
  __syncthreads();
  for (int p = tid; p < VV * VV; p += 128) {
    const int u = p / VV, v2 = p - u * VV;
    float rel[RR];
    #pragma unroll
    for (int j = 0; j < RR; ++j) rel[j] = m1[u][j] - m2[v2][j];
    float t1[HH4];
    #pragma unroll
    for (int k = 0; k < HH4; ++k) {
      float s = b4a[k];
      #pragma unroll
      for (int j = 0; j < RR; ++j) s = fmaf(rel[j], W4a[j * HH4 + k], s);
      t1[k] = silu_f(s);
    }
    const float av = A[u * VV + v2];
    float hc[RR];
    #pragma unroll
    for (int j = 0; j < RR; ++j) {
      float s = b4b[j];
      #pragma unroll
      for (int k = 0; k < HH4; ++k) s = fmaf(t1[k], W4b[k * RR + j], s);
      hc[j] = silu_f(s) + av;
    }
    uint* hp = h2g + (size_t)n * (VV * VV * 5) + (size_t)p * 5;
    hp[0] = h2u(__floats2half2_rn(hc[0], hc[1]));
    hp[1] = h2u(__floats2half2_rn(hc[2], hc[3]));
    hp[2] = h2u(__floats2half2_rn(hc[4], hc[5]));
    hp[3] = h2u(__floats2half2_rn(hc[6], hc[7]));
    hp[4] = h2u(__floats2half2_rn(hc[8], 0.f));
  }
}

// ---------------------------------------------------------------------------
// k3 (R7 + u-split): per (n, tq8, uh2): stage x3 planes (8 KB) to LDS;
// h from global/L1; agg over v + 9->6 silu -> a5s; coalesced 6->64 epilogue.
// Grid 4096, ~10.5 KB LDS, one C1 row per thread -> deeper block pipeline.
// ---------------------------------------------------------------------------
__global__ __launch_bounds__(256) void k3_out(
    const uint* __restrict__ x3g, const uint* __restrict__ h2g,
    const float* __restrict__ W5a, const float* __restrict__ b5a,
    const float* __restrict__ W5b, const float* __restrict__ b5b,
    float* __restrict__ out) {
  const int bid = blockIdx.x;           // ((n*NT + tq) << 1) | uh
  const int uh = bid & 1;
  const int tile = bid >> 1;            // n*NT + tq
  const int n = tile >> 3, tq = tile & 7;
  const int u0 = uh ? 13 : 0;
  const int ucnt = uh ? 12 : 13;
  const int tid = threadIdx.x;
  __shared__ __align__(16) uint x3s[5 * VV * TQ];   // 2000 uints = 8000 B
  __shared__ __align__(16) uint a5s[13 * TQ * 3];   //  624 uints = 2496 B

  {
    const uint4* xsrc = (const uint4*)(x3g + (size_t)tile * (5 * VV * TQ));
    for (int i = tid; i < (5 * VV * TQ) / 4; i += 256)
      ((uint4*)x3s)[i] = xsrc[i];
  }
  __syncthreads();

  // C1: one (u,t) row per thread (rows = ucnt*16 <= 208)
  if (tid < ucnt * TQ) {
    const int ul = tid >> 4, t = tid & 15;
    const int u = u0 + ul;
    const uint* hr = h2g + (size_t)n * (VV * VV * 5) + u * (VV * 5);
    const uint* xr = x3s + t;
    __half2 c0 = u2h(0u), c1 = c0, c2 = c0, c3 = c0, c4 = c0;
    #pragma unroll 5
    for (int v2 = 0; v2 < VV; ++v2) {
      const int xo = v2 * TQ;
      const uint x0 = xr[xo];
      const uint x1 = xr[xo + 400];
      const uint x2 = xr[xo + 800];
      const uint x3 = xr[xo + 1200];
      const uint x4 = xr[xo + 1600];
      const uint* hv = hr + v2 * 5;
      c0 = __hfma2(u2h(hv[0]), u2h(x0), c0);
      c1 = __hfma2(u2h(hv[1]), u2h(x1), c1);
      c2 = __hfma2(u2h(hv[2]), u2h(x2), c2);
      c3 = __hfma2(u2h(hv[3]), u2h(x3), c3);
      c4 = __hfma2(u2h(hv[4]), u2h(x4), c4);
    }
    float ag[RR];
    ag[0] = __low2float(c0); ag[1] = __high2float(c0);
    ag[2] = __low2float(c1); ag[3] = __high2float(c1);
    ag[4] = __low2float(c2); ag[5] = __high2float(c2);
    ag[6] = __low2float(c3); ag[7] = __high2float(c3);
    ag[8] = __low2float(c4);
    float a5v[HH5];
    #pragma unroll
    for (int k = 0; k < HH5; ++k) {
      float s = b5a[k];
      #pragma unroll
      for (int j = 0; j < RR; ++j) s = fmaf(ag[j], W5a[j * HH5 + k], s);
      a5v[k] = silu_f(s);
    }
    a5s[tid * 3 + 0] = h2u(__floats2half2_rn(a5v[0], a5v[1]));
    a5s[tid * 3 + 1] = h2u(__floats2half2_rn(a5v[2], a5v[3]));
    a5s[tid * 3 + 2] = h2u(__floats2half2_rn(a5v[4], a5v[5]));
  }

  // hoist epilogue weights before the barrier
  const int cq = (tid & 15) * 4;
  float4 wb[HH5];
  #pragma unroll
  for (int k = 0; k < HH5; ++k) wb[k] = *(const float4*)(W5b + k * CO + cq);
  const float4 bb = *(const float4*)(b5b + cq);
  __syncthreads();

  // C2: iter u: 16 lanes/row, 16 rows (t) per iter; 1KB-coalesced stores
  const int trow = tid >> 4;            // 0..15
  for (int it = 0; it < ucnt; ++it) {
    const int q = it * 16 + trow;       // local row
    const int u = u0 + it;
    const __half2 p01 = u2h(a5s[q * 3 + 0]);
    const __half2 p23 = u2h(a5s[q * 3 + 1]);
    const __half2 p45 = u2h(a5s[q * 3 + 2]);
    const float a0 = __low2float(p01), a1 = __high2float(p01);
    const float a2 = __low2float(p23), a3 = __high2float(p23);
    const float a4 = __low2float(p45), a5 = __high2float(p45);
    float4 y;
    y.x = silu_f(bb.x + a0 * wb[0].x + a1 * wb[1].x + a2 * wb[2].x +
                 a3 * wb[3].x + a4 * wb[4].x + a5 * wb[5].x);
    y.y = silu_f(bb.y + a0 * wb[0].y + a1 * wb[1].y + a2 * wb[2].y +
                 a3 * wb[3].y + a4 * wb[4].y + a5 * wb[5].y);
    y.z = silu_f(bb.z + a0 * wb[0].z + a1 * wb[1].z + a2 * wb[2].z +
                 a3 * wb[3].z + a4 * wb[4].z + a5 * wb[5].z);
    y.w = silu_f(bb.w + a0 * wb[0].w + a1 * wb[1].w + a2 * wb[2].w +
                 a3 * wb[3].w + a4 * wb[4].w + a5 * wb[5].w);
    float* orow = out +
        ((size_t)(n * VV + u) * TT + tq * TQ + trow) * CO + cq;
    *(float4*)orow = y;
  }
}

extern "C" void kernel_launch(void* const* d_in, const int* in_sizes, int n_in,
                              void* d_out, int out_size, void* d_ws, size_t ws_size,
                              hipStream_t stream) {
  const float* x   = (const float*)d_in[0];
  const float* A   = (const float*)d_in[1];
  const float* W1  = (const float*)d_in[2];
  const float* b1  = (const float*)d_in[3];
  const float* W2  = (const float*)d_in[4];
  const float* b2  = (const float*)d_in[5];
  const float* W3  = (const float*)d_in[6];
  const float* b3  = (const float*)d_in[7];
  const float* W4a = (const float*)d_in[8];
  const float* b4a = (const float*)d_in[9];
  const float* W4b = (const float*)d_in[10];
  const float* b4b = (const float*)d_in[11];
  const float* W5a = (const float*)d_in[12];
  const float* b5a = (const float*)d_in[13];
  const float* W5b = (const float*)d_in[14];
  const float* b5b = (const float*)d_in[15];
  float* out = (float*)d_out;

  char* ws = (char*)d_ws;
  uint*  x3g = (uint*)ws;                        // 256*8*2000*4 = 16,384,000 B
  float* xm  = (float*)(ws + 16384000);          //  1,638,400 B
  uint*  h2g = (uint*)(ws + 16384000 + 1638400); //  3,200,000 B

  hipLaunchKernelGGL(k1_proj, dim3(NN * VV), dim3(128), 0, stream,
                     x, W3, b3, x3g, xm);
  hipLaunchKernelGGL(k2_h, dim3(NN), dim3(128), 0, stream,
                     xm, A, W1, b1, W2, b2, W4a, b4a, W4b, b4b, h2g);
  hipLaunchKernelGGL(k3_out, dim3(NN * NT * 2), dim3(256), 0, stream,
                     x3g, h2g, W5a, b5a, W5b, b5b, out);
}